// Round 1
// baseline (418.035 us; speedup 1.0000x reference)
//
#include <hip/hip_runtime.h>

typedef __bf16 bf16;
typedef bf16 bf16x4 __attribute__((ext_vector_type(4)));
typedef bf16 bf16x8 __attribute__((ext_vector_type(8)));
typedef float f32x4 __attribute__((ext_vector_type(4)));

#define EMBED 512
#define NHEAD 8
#define DEPTH 64
#define BATCH 2
#define SEQ 4096
#define M_TOTAL (BATCH * SEQ)  // 8192

// ---------------- fp32 -> bf16 bulk convert ----------------
__global__ __launch_bounds__(256) void cvt_f32_to_bf16(const float* __restrict__ in,
                                                       bf16* __restrict__ out) {
  int i = (blockIdx.x * 256 + threadIdx.x) * 4;
  float4 f = *(const float4*)(in + i);
  bf16x4 o;
  o[0] = (bf16)f.x; o[1] = (bf16)f.y; o[2] = (bf16)f.z; o[3] = (bf16)f.w;
  *(bf16x4*)(out + i) = o;
}

// ---------------- W[k][n] -> WT[n][k] bf16 (LDS-tiled) ----------------
__global__ __launch_bounds__(256) void transpose_w(const float* __restrict__ W,
                                                   bf16* __restrict__ WT) {
  __shared__ float t[32][33];
  int k0 = blockIdx.x * 32, n0 = blockIdx.y * 32;
  int x = threadIdx.x & 31, y = threadIdx.x >> 5;
#pragma unroll
  for (int yy = y; yy < 32; yy += 8)
    t[yy][x] = W[(size_t)(k0 + yy) * EMBED + n0 + x];
  __syncthreads();
#pragma unroll
  for (int yy = y; yy < 32; yy += 8)
    WT[(size_t)(n0 + yy) * EMBED + k0 + x] = (bf16)t[x][yy];
}

// ---------------- GEMM: Y[m][n] = sum_k A[m][k]*WT[n][k] + bias[n] ----------------
// MODE 0: bf16 out at [b][h][s][d]   (qh / kh)
// MODE 1: bf16 out at [b][h][d][s]   (v transposed, for PV B-fragments)
// MODE 2: fp32 out at [m][n]         (final output)
template <int MODE>
__global__ __launch_bounds__(256) void gemm_proj(const bf16* __restrict__ A,
                                                 const bf16* __restrict__ Bt,
                                                 const float* __restrict__ bias,
                                                 void* __restrict__ out) {
  // stride 40 bf16 = 80 B: 16B-aligned b128 reads, 2-way bank aliasing (free per m136)
  __shared__ __align__(16) bf16 As[64][40];
  __shared__ __align__(16) bf16 Bs[64][40];
  int tid = threadIdx.x;
  int lane = tid & 63, w = tid >> 6;
  int g = lane >> 4, r = lane & 15;
  int n0 = blockIdx.x * 64, m0 = blockIdx.y * 64;
  const f32x4 fz = {0.f, 0.f, 0.f, 0.f};
  f32x4 acc[4];
#pragma unroll
  for (int i = 0; i < 4; i++) acc[i] = fz;
  int srow = tid >> 2, skoff = (tid & 3) * 8;
  const bf16* Ag = A + (size_t)(m0 + srow) * EMBED + skoff;
  const bf16* Bg = Bt + (size_t)(n0 + srow) * EMBED + skoff;

  for (int k0 = 0; k0 < EMBED; k0 += 32) {
    *(bf16x8*)&As[srow][skoff] = *(const bf16x8*)(Ag + k0);
    *(bf16x8*)&Bs[srow][skoff] = *(const bf16x8*)(Bg + k0);
    __syncthreads();
    bf16x8 a = *(const bf16x8*)&As[w * 16 + r][g * 8];
#pragma unroll
    for (int nb = 0; nb < 4; nb++) {
      bf16x8 b = *(const bf16x8*)&Bs[nb * 16 + r][g * 8];
      acc[nb] = __builtin_amdgcn_mfma_f32_16x16x32_bf16(a, b, acc[nb], 0, 0, 0);
    }
    __syncthreads();
  }

#pragma unroll
  for (int nb = 0; nb < 4; nb++) {
    int n = n0 + nb * 16 + r;
    float bv = bias[n];
#pragma unroll
    for (int v = 0; v < 4; v++) {
      int m = m0 + w * 16 + g * 4 + v;  // C/D: row=(lane>>4)*4+v, col=lane&15 (m89/m91)
      float val = acc[nb][v] + bv;
      if (MODE == 2) {
        ((float*)out)[(size_t)m * EMBED + n] = val;
      } else {
        int b = m >> 12, s = m & (SEQ - 1);
        int h = n >> 6, d = n & 63;
        size_t idx = (MODE == 0)
                         ? (((size_t)(b * NHEAD + h) * SEQ + s) * DEPTH + d)
                         : (((size_t)(b * NHEAD + h) * DEPTH + d) * SEQ + s);
        ((bf16*)out)[idx] = (bf16)val;
      }
    }
  }
}

// ---------------- flash attention ----------------
// grid: (SEQ/64, B*H), 256 thr (4 waves x 16 q-rows). KVBLK=64.
__global__ __launch_bounds__(256) void flash_attn(const bf16* __restrict__ qh,
                                                  const bf16* __restrict__ kh,
                                                  const bf16* __restrict__ vT,
                                                  const float* __restrict__ mask,
                                                  bf16* __restrict__ O) {
  __shared__ __align__(16) bf16 Ks[64][72];       // K tile [key][d], stride 144B
  __shared__ __align__(16) bf16 Vs[64][72];       // V^T tile [d][key]
  __shared__ __align__(16) bf16 Ps[4][16][72];    // per-wave P round-trip
  int tid = threadIdx.x;
  int lane = tid & 63, w = tid >> 6;
  int g = lane >> 4, r = lane & 15;
  int bh = blockIdx.y;
  int b = bh >> 3, h = bh & 7;
  int q0 = blockIdx.x * 64;
  const bf16* Qb = qh + (size_t)bh * SEQ * DEPTH;
  const bf16* Kb = kh + (size_t)bh * SEQ * DEPTH;
  const bf16* Vb = vT + (size_t)bh * DEPTH * SEQ;
  const float* maskb = mask + (size_t)b * SEQ;

  // Q fragments live in registers for the whole block
  int qrow = q0 + w * 16 + r;
  bf16x8 aq0 = *(const bf16x8*)(Qb + (size_t)qrow * DEPTH + g * 8);
  bf16x8 aq1 = *(const bf16x8*)(Qb + (size_t)qrow * DEPTH + 32 + g * 8);

  const f32x4 fz = {0.f, 0.f, 0.f, 0.f};
  f32x4 oacc[4];
#pragma unroll
  for (int i = 0; i < 4; i++) oacc[i] = fz;
  float mrun[4], lrun[4];
#pragma unroll
  for (int v = 0; v < 4; v++) { mrun[v] = -__builtin_inff(); lrun[v] = 0.f; }

  int srow = tid >> 2, soff = (tid & 3) * 16;

  for (int kv0 = 0; kv0 < SEQ; kv0 += 64) {
    // ---- stage K [64 keys][64 d] and V^T [64 d][64 keys] ----
    const bf16* kg = Kb + (size_t)(kv0 + srow) * DEPTH + soff;
    *(bf16x8*)&Ks[srow][soff] = *(const bf16x8*)kg;
    *(bf16x8*)&Ks[srow][soff + 8] = *(const bf16x8*)(kg + 8);
    const bf16* vg = Vb + (size_t)srow * SEQ + kv0 + soff;
    *(bf16x8*)&Vs[srow][soff] = *(const bf16x8*)vg;
    *(bf16x8*)&Vs[srow][soff + 8] = *(const bf16x8*)(vg + 8);
    __syncthreads();

    // ---- S = Q K^T (16 q-rows x 64 keys per wave) ----
    f32x4 sacc[4];
#pragma unroll
    for (int i = 0; i < 4; i++) sacc[i] = fz;
#pragma unroll
    for (int cb = 0; cb < 4; cb++) {
      bf16x8 bk0 = *(const bf16x8*)&Ks[cb * 16 + r][g * 8];
      bf16x8 bk1 = *(const bf16x8*)&Ks[cb * 16 + r][32 + g * 8];
      sacc[cb] = __builtin_amdgcn_mfma_f32_16x16x32_bf16(aq0, bk0, sacc[cb], 0, 0, 0);
      sacc[cb] = __builtin_amdgcn_mfma_f32_16x16x32_bf16(aq1, bk1, sacc[cb], 0, 0, 0);
    }

    // ---- scale + additive mask ----
    float sv[4][4];
#pragma unroll
    for (int cb = 0; cb < 4; cb++) {
      float mk = maskb[kv0 + cb * 16 + r] * -1e9f;
#pragma unroll
      for (int v = 0; v < 4; v++) sv[cb][v] = sacc[cb][v] * 0.125f + mk;
    }

    // ---- online softmax, wave-parallel (row r lives on 16 lanes of same g) ----
    float rmax[4];
#pragma unroll
    for (int v = 0; v < 4; v++)
      rmax[v] = fmaxf(fmaxf(sv[0][v], sv[1][v]), fmaxf(sv[2][v], sv[3][v]));
#pragma unroll
    for (int off = 1; off < 16; off <<= 1)
#pragma unroll
      for (int v = 0; v < 4; v++) rmax[v] = fmaxf(rmax[v], __shfl_xor(rmax[v], off));

    float mnew[4], alpha[4];
#pragma unroll
    for (int v = 0; v < 4; v++) {
      mnew[v] = fmaxf(mrun[v], rmax[v]);
      alpha[v] = __expf(mrun[v] - mnew[v]);  // first iter: exp(-inf)=0
    }
    float p[4][4], rsum[4];
#pragma unroll
    for (int v = 0; v < 4; v++) rsum[v] = 0.f;
#pragma unroll
    for (int cb = 0; cb < 4; cb++)
#pragma unroll
      for (int v = 0; v < 4; v++) {
        p[cb][v] = __expf(sv[cb][v] - mnew[v]);
        rsum[v] += p[cb][v];
      }
#pragma unroll
    for (int off = 1; off < 16; off <<= 1)
#pragma unroll
      for (int v = 0; v < 4; v++) rsum[v] += __shfl_xor(rsum[v], off);
#pragma unroll
    for (int v = 0; v < 4; v++) {
      lrun[v] = lrun[v] * alpha[v] + rsum[v];
      mrun[v] = mnew[v];
    }
#pragma unroll
    for (int i = 0; i < 4; i++)
#pragma unroll
      for (int v = 0; v < 4; v++) oacc[i][v] *= alpha[v];

    // ---- P (D-layout) -> per-wave LDS -> A-layout fragments ----
#pragma unroll
    for (int cb = 0; cb < 4; cb++)
#pragma unroll
      for (int v = 0; v < 4; v++)
        Ps[w][g * 4 + v][cb * 16 + r] = (bf16)p[cb][v];

    bf16x8 ap0 = *(const bf16x8*)&Ps[w][r][g * 8];
    bf16x8 ap1 = *(const bf16x8*)&Ps[w][r][32 + g * 8];
#pragma unroll
    for (int db = 0; db < 4; db++) {
      bf16x8 bv0 = *(const bf16x8*)&Vs[db * 16 + r][g * 8];
      bf16x8 bv1 = *(const bf16x8*)&Vs[db * 16 + r][32 + g * 8];
      oacc[db] = __builtin_amdgcn_mfma_f32_16x16x32_bf16(ap0, bv0, oacc[db], 0, 0, 0);
      oacc[db] = __builtin_amdgcn_mfma_f32_16x16x32_bf16(ap1, bv1, oacc[db], 0, 0, 0);
    }
    __syncthreads();
  }

  // ---- epilogue: O /= l, write [B][S][H*D] bf16 ----
  float inv[4];
#pragma unroll
  for (int v = 0; v < 4; v++) inv[v] = 1.f / lrun[v];
#pragma unroll
  for (int db = 0; db < 4; db++)
#pragma unroll
    for (int v = 0; v < 4; v++) {
      int s = q0 + w * 16 + g * 4 + v;
      int d = db * 16 + r;
      O[((size_t)(b * SEQ + s)) * EMBED + h * DEPTH + d] = (bf16)(oacc[db][v] * inv[v]);
    }
}

// ---------------- launch ----------------
extern "C" void kernel_launch(void* const* d_in, const int* in_sizes, int n_in,
                              void* d_out, int out_size, void* d_ws, size_t ws_size,
                              hipStream_t stream) {
  (void)in_sizes; (void)n_in; (void)out_size; (void)ws_size;
  const float* q = (const float*)d_in[0];
  const float* k = (const float*)d_in[1];
  const float* v = (const float*)d_in[2];
  const float* mask = (const float*)d_in[3];
  const float* Wq = (const float*)d_in[4];
  const float* bq = (const float*)d_in[5];
  const float* Wk = (const float*)d_in[6];
  const float* bk = (const float*)d_in[7];
  const float* Wv = (const float*)d_in[8];
  const float* bv = (const float*)d_in[9];
  const float* Wo = (const float*)d_in[10];
  const float* bo = (const float*)d_in[11];

  const size_t NX = (size_t)M_TOTAL * EMBED;  // 4,194,304 elem
  const size_t NW = (size_t)EMBED * EMBED;    // 262,144 elem
  // ws layout (~61 MB total, all bf16):
  bf16* Xq = (bf16*)d_ws;
  bf16* Xk = Xq + NX;
  bf16* Xv = Xk + NX;
  bf16* WTq = Xv + NX;
  bf16* WTk = WTq + NW;
  bf16* WTv = WTk + NW;
  bf16* WTo = WTv + NW;
  bf16* qh = WTo + NW;
  bf16* kh = qh + NX;
  bf16* vT = kh + NX;
  bf16* Ow = vT + NX;

  cvt_f32_to_bf16<<<NX / 1024, 256, 0, stream>>>(q, Xq);
  cvt_f32_to_bf16<<<NX / 1024, 256, 0, stream>>>(k, Xk);
  cvt_f32_to_bf16<<<NX / 1024, 256, 0, stream>>>(v, Xv);
  dim3 tg(16, 16);
  transpose_w<<<tg, 256, 0, stream>>>(Wq, WTq);
  transpose_w<<<tg, 256, 0, stream>>>(Wk, WTk);
  transpose_w<<<tg, 256, 0, stream>>>(Wv, WTv);
  transpose_w<<<tg, 256, 0, stream>>>(Wo, WTo);

  dim3 gg(EMBED / 64, M_TOTAL / 64);
  gemm_proj<0><<<gg, 256, 0, stream>>>(Xq, WTq, bq, qh);
  gemm_proj<0><<<gg, 256, 0, stream>>>(Xk, WTk, bk, kh);
  gemm_proj<1><<<gg, 256, 0, stream>>>(Xv, WTv, bv, vT);

  flash_attn<<<dim3(SEQ / 64, BATCH * NHEAD), 256, 0, stream>>>(qh, kh, vT, mask, Ow);

  gemm_proj<2><<<gg, 256, 0, stream>>>(Ow, WTo, bo, d_out);
}

// Round 2
// 353.593 us; speedup vs baseline: 1.1822x; 1.1822x over previous
//
#include <hip/hip_runtime.h>
#include <stdint.h>

typedef __bf16 bf16;
typedef bf16 bf16x4 __attribute__((ext_vector_type(4)));
typedef bf16 bf16x8 __attribute__((ext_vector_type(8)));
typedef float f32x4 __attribute__((ext_vector_type(4)));
typedef float f32x16 __attribute__((ext_vector_type(16)));

#define EMBED 512
#define NHEAD 8
#define DEPTH 64
#define BATCH 2
#define SEQ 4096
#define M_TOTAL (BATCH * SEQ)  // 8192

#define LOG2E 1.44269504f
#define QSCALE (0.125f * LOG2E)       // folded into q projection
#define MASKC (-1.0e9f * LOG2E)       // mask fma constant (log2 domain)
#define DEFER_THR 10.0f               // T13: skip rescale unless max grows >10 (log2)

// ---------------- fp32 -> bf16 bulk convert ----------------
__global__ __launch_bounds__(256) void cvt_f32_to_bf16(const float* __restrict__ in,
                                                       bf16* __restrict__ out) {
  int i = (blockIdx.x * 256 + threadIdx.x) * 4;
  float4 f = *(const float4*)(in + i);
  bf16x4 o;
  o[0] = (bf16)f.x; o[1] = (bf16)f.y; o[2] = (bf16)f.z; o[3] = (bf16)f.w;
  *(bf16x4*)(out + i) = o;
}

// ---------------- W[k][n] -> WT[n][k] bf16 (LDS-tiled) ----------------
__global__ __launch_bounds__(256) void transpose_w(const float* __restrict__ W,
                                                   bf16* __restrict__ WT) {
  __shared__ float t[32][33];
  int k0 = blockIdx.x * 32, n0 = blockIdx.y * 32;
  int x = threadIdx.x & 31, y = threadIdx.x >> 5;
#pragma unroll
  for (int yy = y; yy < 32; yy += 8)
    t[yy][x] = W[(size_t)(k0 + yy) * EMBED + n0 + x];
  __syncthreads();
#pragma unroll
  for (int yy = y; yy < 32; yy += 8)
    WT[(size_t)(n0 + yy) * EMBED + k0 + x] = (bf16)t[x][yy];
}

// ---------------- GEMM: Y[m][n] = (sum_k A[m][k]*WT[n][k] + bias[n]) * scale ----
// MODE 0: bf16 out at [b][h][s][d]   (qh / kh)
// MODE 1: bf16 out at [b][h][d][s]   (v transposed, for PV B-fragments)
// MODE 2: fp32 out at [m][n]         (final output)
template <int MODE>
__global__ __launch_bounds__(256) void gemm_proj(const bf16* __restrict__ A,
                                                 const bf16* __restrict__ Bt,
                                                 const float* __restrict__ bias,
                                                 void* __restrict__ out, float scale) {
  __shared__ __align__(16) bf16 As[64][40];
  __shared__ __align__(16) bf16 Bs[64][40];
  int tid = threadIdx.x;
  int lane = tid & 63, w = tid >> 6;
  int g = lane >> 4, r = lane & 15;
  int n0 = blockIdx.x * 64, m0 = blockIdx.y * 64;
  const f32x4 fz = {0.f, 0.f, 0.f, 0.f};
  f32x4 acc[4];
#pragma unroll
  for (int i = 0; i < 4; i++) acc[i] = fz;
  int srow = tid >> 2, skoff = (tid & 3) * 8;
  const bf16* Ag = A + (size_t)(m0 + srow) * EMBED + skoff;
  const bf16* Bg = Bt + (size_t)(n0 + srow) * EMBED + skoff;

  for (int k0 = 0; k0 < EMBED; k0 += 32) {
    *(bf16x8*)&As[srow][skoff] = *(const bf16x8*)(Ag + k0);
    *(bf16x8*)&Bs[srow][skoff] = *(const bf16x8*)(Bg + k0);
    __syncthreads();
    bf16x8 a = *(const bf16x8*)&As[w * 16 + r][g * 8];
#pragma unroll
    for (int nb = 0; nb < 4; nb++) {
      bf16x8 b = *(const bf16x8*)&Bs[nb * 16 + r][g * 8];
      acc[nb] = __builtin_amdgcn_mfma_f32_16x16x32_bf16(a, b, acc[nb], 0, 0, 0);
    }
    __syncthreads();
  }

#pragma unroll
  for (int nb = 0; nb < 4; nb++) {
    int n = n0 + nb * 16 + r;
    float bv = bias[n];
#pragma unroll
    for (int v = 0; v < 4; v++) {
      int m = m0 + w * 16 + g * 4 + v;  // C/D: row=(lane>>4)*4+v, col=lane&15
      float val = (acc[nb][v] + bv) * scale;
      if (MODE == 2) {
        ((float*)out)[(size_t)m * EMBED + n] = val;
      } else {
        int b = m >> 12, s = m & (SEQ - 1);
        int h = n >> 6, d = n & 63;
        size_t idx = (MODE == 0)
                         ? (((size_t)(b * NHEAD + h) * SEQ + s) * DEPTH + d)
                         : (((size_t)(b * NHEAD + h) * DEPTH + d) * SEQ + s);
        ((bf16*)out)[idx] = (bf16)val;
      }
    }
  }
}

// ---------------- helpers ----------------
__device__ inline void gload16(const void* g, void* l) {
  __builtin_amdgcn_global_load_lds((const __attribute__((address_space(1))) unsigned*)g,
                                   (__attribute__((address_space(3))) unsigned*)l, 16, 0, 0);
}
__device__ inline uint32_t cvtpk(float a, float b) {
  uint32_t r;
  asm volatile("v_cvt_pk_bf16_f32 %0, %1, %2" : "=v"(r) : "v"(a), "v"(b));
  return r;
}
__device__ inline void plswap(uint32_t& a, uint32_t& b) {
  asm volatile("v_permlane32_swap_b32 %0, %1" : "+v"(a), "+v"(b));
}
union U4 { uint32_t u[4]; bf16x8 v; };

// ---------------- flash attention, swapped-QK^T (m214 structure) ----------------
// grid (SEQ/256, B*H), 512 thr = 8 waves x 32 q-rows. KVBLK=64, 32x32x16 MFMA.
// S^T layout: lane l31 = q, regs = keys (crow). Softmax fully lane-local per q.
__global__ __launch_bounds__(512) void flash_attn(const bf16* __restrict__ qh,
                                                  const bf16* __restrict__ kh,
                                                  const bf16* __restrict__ vT,
                                                  const float* __restrict__ mask,
                                                  bf16* __restrict__ O) {
  // double-buffered K [64 key][64 d] and V^T [64 d][64 key], XOR-swizzled 16B units
  __shared__ __align__(16) bf16 Ks[2][4096];
  __shared__ __align__(16) bf16 Vs[2][4096];
  int tid = threadIdx.x;
  int lane = tid & 63, w = tid >> 6;
  int l31 = lane & 31, hi = lane >> 5, l7 = lane & 7;
  int bh = blockIdx.y, b = bh >> 3, h = bh & 7;
  int q0 = blockIdx.x * 256;
  const bf16* Qb = qh + (size_t)bh * SEQ * DEPTH;
  const bf16* Kb = kh + (size_t)bh * SEQ * DEPTH;
  const bf16* Vb = vT + (size_t)bh * DEPTH * SEQ;
  const float* maskb = mask + (size_t)b * SEQ;

  // staging address precompute: unit u=tid covers LDS bytes u*16 (linear dest);
  // source column pre-swizzled (rule 21: inverse-swz source + swz read)
  int srow = tid >> 3;
  int scs = (tid & 7) ^ (srow & 7);
  const bf16* kg0 = Kb + (size_t)srow * DEPTH + scs * 8;
  const bf16* vg0 = Vb + (size_t)srow * SEQ + scs * 8;
  bf16* kdst0 = &Ks[0][w * 512];
  bf16* vdst0 = &Vs[0][w * 512];

  // prologue stage tile 0
  gload16(kg0, kdst0);
  gload16(vg0, vdst0);

  // Q fragments (B-operand): lane holds Q[q0+w*32+l31][s*16+hi*8 .. +7], whole block
  bf16x8 qf[4];
  {
    const bf16* qp = Qb + (size_t)(q0 + w * 32 + l31) * DEPTH + hi * 8;
#pragma unroll
    for (int s = 0; s < 4; s++) qf[s] = *(const bf16x8*)(qp + s * 16);
  }

  f32x16 oacc[2];
#pragma unroll
  for (int nb = 0; nb < 2; nb++)
#pragma unroll
    for (int i = 0; i < 16; i++) oacc[nb][i] = 0.f;
  float mrun = -__builtin_inff(), lrun = 0.f;

  __syncthreads();  // tile 0 staged

  int cur = 0;
  for (int t = 0; t < SEQ / 64; ++t) {
    int kv = t * 64;
    // ---- prefetch next tile into buf cur^1 (drained at the barrier below) ----
    if (t + 1 < SEQ / 64) {
      gload16(kg0 + (size_t)(kv + 64) * DEPTH, (cur ? kdst0 : &Ks[1][w * 512]));
      gload16(vg0 + (kv + 64), (cur ? vdst0 : &Vs[1][w * 512]));
    }

    const bf16* Kcur = Ks[cur];
    const bf16* Vcur = Vs[cur];

    // ---- S^T = K Q^T : sacc[m2][reg] = S[key=m2*32+crow(reg,hi)][q=l31] ----
    f32x16 sacc[2];
#pragma unroll
    for (int m2 = 0; m2 < 2; m2++) {
#pragma unroll
      for (int i = 0; i < 16; i++) sacc[m2][i] = 0.f;
#pragma unroll
      for (int s = 0; s < 4; s++) {
        bf16x8 kf = *(const bf16x8*)(Kcur + (m2 * 32 + l31) * 64 + (((s * 2 + hi) ^ l7) * 8));
        sacc[m2] = __builtin_amdgcn_mfma_f32_32x32x16_bf16(kf, qf[s], sacc[m2], 0, 0, 0);
      }
    }

    // ---- additive mask (fma with MASKC folds the *-1e9*log2e) ----
    const float* mmp = maskb + kv;
#pragma unroll
    for (int m2 = 0; m2 < 2; m2++)
#pragma unroll
      for (int g = 0; g < 4; g++) {
        f32x4 f = *(const f32x4*)(mmp + m2 * 32 + g * 8 + 4 * hi);
#pragma unroll
        for (int i = 0; i < 4; i++) sacc[m2][4 * g + i] = fmaf(f[i], MASKC, sacc[m2][4 * g + i]);
      }

    // ---- row max: 31 in-lane + one cross-half exchange ----
    float pmax = sacc[0][0];
#pragma unroll
    for (int m2 = 0; m2 < 2; m2++)
#pragma unroll
      for (int i = 0; i < 16; i++)
        if (m2 + i) pmax = fmaxf(pmax, sacc[m2][i]);
    pmax = fmaxf(pmax, __shfl_xor(pmax, 32));

    // ---- defer-max (T13): rescale only if max grew past threshold ----
    if (__any(pmax > mrun + DEFER_THR)) {
      float mnew = fmaxf(mrun, pmax);
      float alpha = exp2f(mrun - mnew);  // first tile: exp2(-inf)=0
      lrun *= alpha;
      mrun = mnew;
#pragma unroll
      for (int r = 0; r < 16; r++) {
        float af = __shfl(alpha, (r & 3) + 8 * (r >> 2) + 4 * hi);
        oacc[0][r] *= af;
        oacc[1][r] *= af;
      }
    }

    // ---- P = exp2(S - m), row sum ----
    float p[32];
    float rsv[4] = {0.f, 0.f, 0.f, 0.f};
#pragma unroll
    for (int m2 = 0; m2 < 2; m2++)
#pragma unroll
      for (int i = 0; i < 16; i++) {
        float pv = exp2f(sacc[m2][i] - mrun);
        p[m2 * 16 + i] = pv;
        rsv[i & 3] += pv;
      }
    float rsum = (rsv[0] + rsv[1]) + (rsv[2] + rsv[3]);
    rsum += __shfl_xor(rsum, 32);
    lrun += rsum;

    // ---- P -> A-operand frags in-register (T12: cvt_pk + permlane32_swap) ----
    bf16x8 pa[4];
#pragma unroll
    for (int m2 = 0; m2 < 2; m2++) {
      uint32_t c0 = cvtpk(p[m2 * 16 + 0], p[m2 * 16 + 1]);
      uint32_t c1 = cvtpk(p[m2 * 16 + 2], p[m2 * 16 + 3]);
      uint32_t d0 = cvtpk(p[m2 * 16 + 4], p[m2 * 16 + 5]);
      uint32_t d1 = cvtpk(p[m2 * 16 + 6], p[m2 * 16 + 7]);
      plswap(c0, d0);
      plswap(c1, d1);
      U4 e; e.u[0] = c0; e.u[1] = c1; e.u[2] = d0; e.u[3] = d1;
      pa[m2 * 2 + 0] = e.v;
      uint32_t c2 = cvtpk(p[m2 * 16 + 8], p[m2 * 16 + 9]);
      uint32_t c3 = cvtpk(p[m2 * 16 + 10], p[m2 * 16 + 11]);
      uint32_t d2 = cvtpk(p[m2 * 16 + 12], p[m2 * 16 + 13]);
      uint32_t d3 = cvtpk(p[m2 * 16 + 14], p[m2 * 16 + 15]);
      plswap(c2, d2);
      plswap(c3, d3);
      U4 o; o.u[0] = c2; o.u[1] = c3; o.u[2] = d2; o.u[3] = d3;
      pa[m2 * 2 + 1] = o.v;
    }

    // ---- O += P V ----
#pragma unroll
    for (int nb = 0; nb < 2; nb++)
#pragma unroll
      for (int ks = 0; ks < 4; ks++) {
        bf16x8 vf = *(const bf16x8*)(Vcur + (nb * 32 + l31) * 64 + (((ks * 2 + hi) ^ l7) * 8));
        oacc[nb] = __builtin_amdgcn_mfma_f32_32x32x16_bf16(pa[ks], vf, oacc[nb], 0, 0, 0);
      }

    __syncthreads();  // next tile staged + all waves done with buf[cur]
    cur ^= 1;
  }

  // ---- epilogue: O /= l, write [B][S][E] bf16 ----
  float invl = 1.0f / lrun;
  bf16* Ob = O + ((size_t)(b * SEQ + q0 + w * 32)) * EMBED + h * DEPTH + l31;
#pragma unroll
  for (int r = 0; r < 16; r++) {
    int cr = (r & 3) + 8 * (r >> 2) + 4 * hi;
    float iv = __shfl(invl, cr);
    Ob[(size_t)cr * EMBED + 0] = (bf16)(oacc[0][r] * iv);
    Ob[(size_t)cr * EMBED + 32] = (bf16)(oacc[1][r] * iv);
  }
}

// ---------------- launch ----------------
extern "C" void kernel_launch(void* const* d_in, const int* in_sizes, int n_in,
                              void* d_out, int out_size, void* d_ws, size_t ws_size,
                              hipStream_t stream) {
  (void)in_sizes; (void)n_in; (void)out_size; (void)ws_size;
  const float* q = (const float*)d_in[0];
  const float* k = (const float*)d_in[1];
  const float* v = (const float*)d_in[2];
  const float* mask = (const float*)d_in[3];
  const float* Wq = (const float*)d_in[4];
  const float* bq = (const float*)d_in[5];
  const float* Wk = (const float*)d_in[6];
  const float* bk = (const float*)d_in[7];
  const float* Wv = (const float*)d_in[8];
  const float* bv = (const float*)d_in[9];
  const float* Wo = (const float*)d_in[10];
  const float* bo = (const float*)d_in[11];

  const size_t NX = (size_t)M_TOTAL * EMBED;
  const size_t NW = (size_t)EMBED * EMBED;
  bf16* Xq = (bf16*)d_ws;
  bf16* Xk = Xq + NX;
  bf16* Xv = Xk + NX;
  bf16* WTq = Xv + NX;
  bf16* WTk = WTq + NW;
  bf16* WTv = WTk + NW;
  bf16* WTo = WTv + NW;
  bf16* qh = WTo + NW;
  bf16* kh = qh + NX;
  bf16* vT = kh + NX;
  bf16* Ow = vT + NX;

  cvt_f32_to_bf16<<<NX / 1024, 256, 0, stream>>>(q, Xq);
  cvt_f32_to_bf16<<<NX / 1024, 256, 0, stream>>>(k, Xk);
  cvt_f32_to_bf16<<<NX / 1024, 256, 0, stream>>>(v, Xv);
  dim3 tg(16, 16);
  transpose_w<<<tg, 256, 0, stream>>>(Wq, WTq);
  transpose_w<<<tg, 256, 0, stream>>>(Wk, WTk);
  transpose_w<<<tg, 256, 0, stream>>>(Wv, WTv);
  transpose_w<<<tg, 256, 0, stream>>>(Wo, WTo);

  dim3 gg(EMBED / 64, M_TOTAL / 64);
  gemm_proj<0><<<gg, 256, 0, stream>>>(Xq, WTq, bq, qh, QSCALE);  // q pre-scaled (log2 domain)
  gemm_proj<0><<<gg, 256, 0, stream>>>(Xk, WTk, bk, kh, 1.0f);
  gemm_proj<1><<<gg, 256, 0, stream>>>(Xv, WTv, bv, vT, 1.0f);

  flash_attn<<<dim3(SEQ / 256, BATCH * NHEAD), 512, 0, stream>>>(qh, kh, vT, mask, Ow);

  gemm_proj<2><<<gg, 256, 0, stream>>>(Ow, WTo, bo, d_out, 1.0f);
}

// Round 3
// 255.565 us; speedup vs baseline: 1.6357x; 1.3836x over previous
//
#include <hip/hip_runtime.h>
#include <stdint.h>

typedef __bf16 bf16;
typedef bf16 bf16x8 __attribute__((ext_vector_type(8)));
typedef float f32x4 __attribute__((ext_vector_type(4)));
typedef float f32x16 __attribute__((ext_vector_type(16)));

#define EMBED 512
#define NHEAD 8
#define DEPTH 64
#define BATCH 2
#define SEQ 4096
#define M_TOTAL (BATCH * SEQ)  // 8192

#define LOG2E 1.44269504f
#define QSCALE (0.125f * LOG2E)  // folded into q projection (log2 domain)
#define MASKC (-1.0e9f * LOG2E)
#define DEFER_THR 10.0f

// ---------------- helpers ----------------
__device__ __forceinline__ void gload16(const void* g, void* l) {
  __builtin_amdgcn_global_load_lds((const __attribute__((address_space(1))) unsigned*)g,
                                   (__attribute__((address_space(3))) unsigned*)l, 16, 0, 0);
}
__device__ __forceinline__ uint32_t cvtpk(float a, float b) {
  uint32_t r;
  asm volatile("v_cvt_pk_bf16_f32 %0, %1, %2" : "=v"(r) : "v"(a), "v"(b));
  return r;
}
__device__ __forceinline__ void plswap(uint32_t& a, uint32_t& b) {
  asm volatile("v_permlane32_swap_b32 %0, %1" : "+v"(a), "+v"(b));
}
// opaque copy so the two permlane operands can't be value-numbered into one reg
__device__ __forceinline__ float vdup(float x) {
  float r;
  asm volatile("v_mov_b32 %0, %1" : "=v"(r) : "v"(x));
  return r;
}
__device__ __forceinline__ float cross_max(float x) {  // max with lane^32 partner
  float a = x, b = vdup(x);
  asm volatile("v_permlane32_swap_b32 %0, %1" : "+v"(a), "+v"(b));
  return fmaxf(a, b);
}
__device__ __forceinline__ float cross_sum(float x) {  // self + lane^32 partner
  float a = x, b = vdup(x);
  asm volatile("v_permlane32_swap_b32 %0, %1" : "+v"(a), "+v"(b));
  return a + b;
}
union U4 { uint32_t u[4]; bf16x8 v; };

// ---------------- fused fp32 -> bf16 convert (q,k,v in one dispatch) ----------------
__global__ __launch_bounds__(256) void cvt3(const float* __restrict__ q, const float* __restrict__ k,
                                            const float* __restrict__ v, bf16* __restrict__ oq,
                                            bf16* __restrict__ ok, bf16* __restrict__ ov) {
  int z = blockIdx.y;
  const float* in = z == 0 ? q : (z == 1 ? k : v);
  bf16* out = z == 0 ? oq : (z == 1 ? ok : ov);
  size_t i = ((size_t)blockIdx.x * 256 + threadIdx.x) * 8;
  float4 f0 = *(const float4*)(in + i);
  float4 f1 = *(const float4*)(in + i + 4);
  bf16x8 o;
  o[0] = (bf16)f0.x; o[1] = (bf16)f0.y; o[2] = (bf16)f0.z; o[3] = (bf16)f0.w;
  o[4] = (bf16)f1.x; o[5] = (bf16)f1.y; o[6] = (bf16)f1.z; o[7] = (bf16)f1.w;
  *(bf16x8*)(out + i) = o;
}

// ---------------- W[k][n] -> WT[n][k] bf16, all 4 weights in one dispatch ----------------
__global__ __launch_bounds__(256) void transpose4(const float* __restrict__ W0, const float* __restrict__ W1,
                                                  const float* __restrict__ W2, const float* __restrict__ W3,
                                                  bf16* __restrict__ T0, bf16* __restrict__ T1,
                                                  bf16* __restrict__ T2, bf16* __restrict__ T3) {
  int z = blockIdx.z;
  const float* W = z == 0 ? W0 : (z == 1 ? W1 : (z == 2 ? W2 : W3));
  bf16* WT = z == 0 ? T0 : (z == 1 ? T1 : (z == 2 ? T2 : T3));
  __shared__ float t[32][33];
  int k0 = blockIdx.x * 32, n0 = blockIdx.y * 32;
  int x = threadIdx.x & 31, y = threadIdx.x >> 5;
#pragma unroll
  for (int yy = y; yy < 32; yy += 8)
    t[yy][x] = W[(size_t)(k0 + yy) * EMBED + n0 + x];
  __syncthreads();
#pragma unroll
  for (int yy = y; yy < 32; yy += 8)
    WT[(size_t)(n0 + yy) * EMBED + k0 + x] = (bf16)t[x][yy];
}

// ---------------- 128x128 GEMM body (m97 structure: BK=64, gload_lds w16, XOR swz) ----
// Y[m][n] = (sum_k A[m][k]*Bt[n][k] + bias[n]) * scale
// mode 0: bf16 out [b][h][s][d]; mode 1: bf16 out [b][h][d][s]; mode 2: f32 out [m][n]
__device__ __forceinline__ void gemm128_body(const bf16* __restrict__ A, const bf16* __restrict__ Bt,
                                             const float* __restrict__ bias, void* __restrict__ out,
                                             float scale, int mode) {
  __shared__ __align__(16) bf16 As[128 * 64];
  __shared__ __align__(16) bf16 Bs[128 * 64];
  int tid = threadIdx.x, lane = tid & 63, w = tid >> 6;
  int g = lane >> 4, r = lane & 15;
  int n0 = blockIdx.x * 128, m0 = blockIdx.y * 128;
  int wr = (w >> 1) * 64, wc = (w & 1) * 64;

  f32x4 acc[4][4];
#pragma unroll
  for (int m = 0; m < 4; m++)
#pragma unroll
    for (int n = 0; n < 4; n++)
#pragma unroll
      for (int i = 0; i < 4; i++) acc[m][n][i] = 0.f;

  // staging: unit u = lane + (i*4+w)*64 covers LDS bytes u*16; source col pre-swizzled
  size_t aoff[4], boff[4];
#pragma unroll
  for (int i = 0; i < 4; i++) {
    int u = w * 64 + lane + i * 256;
    int row = u >> 3, scs = (u & 7) ^ (row & 7);
    aoff[i] = (size_t)(m0 + row) * EMBED + scs * 8;
    boff[i] = (size_t)(n0 + row) * EMBED + scs * 8;
  }

  for (int k0 = 0; k0 < EMBED; k0 += 64) {
#pragma unroll
    for (int i = 0; i < 4; i++) {
      gload16(A + aoff[i] + k0, &As[(w + i * 4) * 512]);
      gload16(Bt + boff[i] + k0, &Bs[(w + i * 4) * 512]);
    }
    __syncthreads();
#pragma unroll
    for (int kk = 0; kk < 64; kk += 32) {
      bf16x8 af[4], bf_[4];
#pragma unroll
      for (int m = 0; m < 4; m++) {
        int row = wr + m * 16 + r;
        af[m] = *(const bf16x8*)&As[row * 64 + (((kk >> 3) + g) ^ (r & 7)) * 8];
      }
#pragma unroll
      for (int n = 0; n < 4; n++) {
        int col = wc + n * 16 + r;
        bf_[n] = *(const bf16x8*)&Bs[col * 64 + (((kk >> 3) + g) ^ (r & 7)) * 8];
      }
      __builtin_amdgcn_s_setprio(1);
#pragma unroll
      for (int m = 0; m < 4; m++)
#pragma unroll
        for (int n = 0; n < 4; n++)
          acc[m][n] = __builtin_amdgcn_mfma_f32_16x16x32_bf16(af[m], bf_[n], acc[m][n], 0, 0, 0);
      __builtin_amdgcn_s_setprio(0);
    }
    __syncthreads();
  }

#pragma unroll
  for (int n = 0; n < 4; n++) {
    int ncol = n0 + wc + n * 16 + r;
    float bv = bias[ncol];
#pragma unroll
    for (int m = 0; m < 4; m++)
#pragma unroll
      for (int v_ = 0; v_ < 4; v_++) {
        int mrow = m0 + wr + m * 16 + g * 4 + v_;
        float val = (acc[m][n][v_] + bv) * scale;
        if (mode == 2) {
          ((float*)out)[(size_t)mrow * EMBED + ncol] = val;
        } else {
          int b = mrow >> 12, s = mrow & (SEQ - 1);
          int h = ncol >> 6, d = ncol & 63;
          size_t idx = (mode == 0) ? ((((size_t)(b * NHEAD + h)) * SEQ + s) * DEPTH + d)
                                   : ((((size_t)(b * NHEAD + h)) * DEPTH + d) * SEQ + s);
          ((bf16*)out)[idx] = (bf16)val;
        }
      }
  }
}

// batched Q/K/V projections: blockIdx.z selects which (768 blocks -> 3 blocks/CU overlap)
__global__ __launch_bounds__(256, 3) void gemm_qkv(const bf16* __restrict__ Xq, const bf16* __restrict__ Xk,
                                                   const bf16* __restrict__ Xv, const bf16* __restrict__ Tq,
                                                   const bf16* __restrict__ Tk, const bf16* __restrict__ Tv,
                                                   const float* __restrict__ bq, const float* __restrict__ bk,
                                                   const float* __restrict__ bv, bf16* __restrict__ qh,
                                                   bf16* __restrict__ kh, bf16* __restrict__ vT) {
  int z = blockIdx.z;
  const bf16* A = z == 0 ? Xq : (z == 1 ? Xk : Xv);
  const bf16* Bt = z == 0 ? Tq : (z == 1 ? Tk : Tv);
  const float* bias = z == 0 ? bq : (z == 1 ? bk : bv);
  void* out = z == 0 ? (void*)qh : (z == 1 ? (void*)kh : (void*)vT);
  float scale = z == 0 ? QSCALE : 1.0f;
  int mode = z == 2 ? 1 : 0;
  gemm128_body(A, Bt, bias, out, scale, mode);
}

__global__ __launch_bounds__(256, 3) void gemm_o(const bf16* __restrict__ A, const bf16* __restrict__ Bt,
                                                 const float* __restrict__ bias, float* __restrict__ out) {
  gemm128_body(A, Bt, bias, out, 1.0f, 2);
}

// ---------------- flash attention (swapped-QK^T, 4-wave blocks) ----------------
// grid (SEQ/128, B*H) = 512 blocks, 256 thr = 4 waves x 32 q-rows. KVBLK=64, 32x32x16.
__global__ __launch_bounds__(256, 2) void flash_attn(const bf16* __restrict__ qh,
                                                     const bf16* __restrict__ kh,
                                                     const bf16* __restrict__ vT,
                                                     const float* __restrict__ mask,
                                                     bf16* __restrict__ O) {
  __shared__ __align__(16) bf16 Ks[2][4096];
  __shared__ __align__(16) bf16 Vs[2][4096];
  int tid = threadIdx.x;
  int lane = tid & 63, w = tid >> 6;
  int l31 = lane & 31, hi = lane >> 5, l7 = lane & 7;
  int bh = blockIdx.y, b = bh >> 3, h = bh & 7;
  int q0 = blockIdx.x * 128;
  const bf16* Qb = qh + (size_t)bh * SEQ * DEPTH;
  const bf16* Kb = kh + (size_t)bh * SEQ * DEPTH;
  const bf16* Vb = vT + (size_t)bh * DEPTH * SEQ;
  const float* maskb = mask + (size_t)b * SEQ;

  // staging: unit u = tid covers Ks bytes u*16 (rows 0-31); u+256 covers rows 32-63.
  // source col pre-swizzled (rule 21): scs = (u&7) ^ (row&7)
  int srow = tid >> 3;
  int scs = (tid & 7) ^ (srow & 7);
  const bf16* kg0 = Kb + (size_t)srow * DEPTH + scs * 8;
  const bf16* vg0 = Vb + (size_t)srow * SEQ + scs * 8;
  bf16* kd0 = &Ks[0][w * 512];
  bf16* kd1 = &Ks[1][w * 512];
  bf16* vd0 = &Vs[0][w * 512];
  bf16* vd1 = &Vs[1][w * 512];

  // prologue: stage tile 0 into buf 0
  gload16(kg0, kd0);
  gload16(kg0 + 2048, kd0 + 2048);          // rows 32-63: +32*DEPTH
  gload16(vg0, vd0);
  gload16(vg0 + 32 * SEQ, vd0 + 2048);

  // Q fragments (B-operand), resident whole kernel
  bf16x8 qf[4];
  {
    const bf16* qp = Qb + (size_t)(q0 + w * 32 + l31) * DEPTH + hi * 8;
#pragma unroll
    for (int s = 0; s < 4; s++) qf[s] = *(const bf16x8*)(qp + s * 16);
  }

  f32x16 oacc[2];
#pragma unroll
  for (int nb = 0; nb < 2; nb++)
#pragma unroll
    for (int i = 0; i < 16; i++) oacc[nb][i] = 0.f;
  float mrun = -__builtin_inff(), lrun = 0.f;

  __syncthreads();

  int cur = 0;
  for (int t = 0; t < SEQ / 64; ++t) {
    int kv = t * 64;
    // ---- prefetch next tile (issue-early; drained by loop-end barrier) ----
    if (t + 1 < SEQ / 64) {
      const bf16* kg = kg0 + (size_t)(kv + 64) * DEPTH;
      const bf16* vg = vg0 + (kv + 64);
      bf16* kd = cur ? kd0 : kd1;
      bf16* vd = cur ? vd0 : vd1;
      gload16(kg, kd);
      gload16(kg + 2048, kd + 2048);
      gload16(vg, vd);
      gload16(vg + 32 * SEQ, vd + 2048);
    }
    // ---- hoist mask loads (global latency hides under QK^T) ----
    f32x4 mf[8];
#pragma unroll
    for (int m2 = 0; m2 < 2; m2++)
#pragma unroll
      for (int g = 0; g < 4; g++)
        mf[m2 * 4 + g] = *(const f32x4*)(maskb + kv + m2 * 32 + g * 8 + 4 * hi);

    const bf16* Kcur = cur ? Ks[1] : Ks[0];
    const bf16* Vcur = cur ? Vs[1] : Vs[0];

    // ---- S^T = K Q^T ----
    f32x16 sacc[2];
#pragma unroll
    for (int m2 = 0; m2 < 2; m2++) {
#pragma unroll
      for (int i = 0; i < 16; i++) sacc[m2][i] = 0.f;
    }
    __builtin_amdgcn_s_setprio(1);
#pragma unroll
    for (int m2 = 0; m2 < 2; m2++)
#pragma unroll
      for (int s = 0; s < 4; s++) {
        bf16x8 kf = *(const bf16x8*)(Kcur + (m2 * 32 + l31) * 64 + (((s * 2 + hi) ^ l7) * 8));
        sacc[m2] = __builtin_amdgcn_mfma_f32_32x32x16_bf16(kf, qf[s], sacc[m2], 0, 0, 0);
      }
    __builtin_amdgcn_s_setprio(0);

    // ---- mask fma ----
#pragma unroll
    for (int m2 = 0; m2 < 2; m2++)
#pragma unroll
      for (int g = 0; g < 4; g++)
#pragma unroll
        for (int i = 0; i < 4; i++)
          sacc[m2][4 * g + i] = fmaf(mf[m2 * 4 + g][i], MASKC, sacc[m2][4 * g + i]);

    // ---- row max: balanced tree (depth 5) + permlane cross-half ----
    float tmx[16];
#pragma unroll
    for (int i = 0; i < 16; i++) tmx[i] = fmaxf(sacc[0][i], sacc[1][i]);
#pragma unroll
    for (int i = 0; i < 8; i++) tmx[i] = fmaxf(tmx[i], tmx[i + 8]);
#pragma unroll
    for (int i = 0; i < 4; i++) tmx[i] = fmaxf(tmx[i], tmx[i + 4]);
    float pmax = fmaxf(fmaxf(tmx[0], tmx[1]), fmaxf(tmx[2], tmx[3]));
    pmax = cross_max(pmax);

    // ---- defer-max (T13) ----
    if (__any(pmax > mrun + DEFER_THR)) {
      float mnew = fmaxf(mrun, pmax);
      float alpha = exp2f(mrun - mnew);
      lrun *= alpha;
      mrun = mnew;
#pragma unroll
      for (int r = 0; r < 16; r++) {
        float af = __shfl(alpha, (r & 3) + 8 * (r >> 2) + 4 * hi);
        oacc[0][r] *= af;
        oacc[1][r] *= af;
      }
    }

    // ---- P = exp2(S - m), row sum ----
    float p[32];
    float rsv[4] = {0.f, 0.f, 0.f, 0.f};
#pragma unroll
    for (int m2 = 0; m2 < 2; m2++)
#pragma unroll
      for (int i = 0; i < 16; i++) {
        float pv = __builtin_amdgcn_exp2f(sacc[m2][i] - mrun);
        p[m2 * 16 + i] = pv;
        rsv[i & 3] += pv;
      }
    float rsum = (rsv[0] + rsv[1]) + (rsv[2] + rsv[3]);
    lrun += cross_sum(rsum);

    // ---- P -> A-frags in-register (T12) ----
    bf16x8 pa[4];
#pragma unroll
    for (int m2 = 0; m2 < 2; m2++) {
      uint32_t c0 = cvtpk(p[m2 * 16 + 0], p[m2 * 16 + 1]);
      uint32_t c1 = cvtpk(p[m2 * 16 + 2], p[m2 * 16 + 3]);
      uint32_t d0 = cvtpk(p[m2 * 16 + 4], p[m2 * 16 + 5]);
      uint32_t d1 = cvtpk(p[m2 * 16 + 6], p[m2 * 16 + 7]);
      plswap(c0, d0);
      plswap(c1, d1);
      U4 e; e.u[0] = c0; e.u[1] = c1; e.u[2] = d0; e.u[3] = d1;
      pa[m2 * 2 + 0] = e.v;
      uint32_t c2 = cvtpk(p[m2 * 16 + 8], p[m2 * 16 + 9]);
      uint32_t c3 = cvtpk(p[m2 * 16 + 10], p[m2 * 16 + 11]);
      uint32_t d2 = cvtpk(p[m2 * 16 + 12], p[m2 * 16 + 13]);
      uint32_t d3 = cvtpk(p[m2 * 16 + 14], p[m2 * 16 + 15]);
      plswap(c2, d2);
      plswap(c3, d3);
      U4 o; o.u[0] = c2; o.u[1] = c3; o.u[2] = d2; o.u[3] = d3;
      pa[m2 * 2 + 1] = o.v;
    }

    // ---- O += P V ----
    __builtin_amdgcn_s_setprio(1);
#pragma unroll
    for (int nb = 0; nb < 2; nb++)
#pragma unroll
      for (int ks = 0; ks < 4; ks++) {
        bf16x8 vf = *(const bf16x8*)(Vcur + (nb * 32 + l31) * 64 + (((ks * 2 + hi) ^ l7) * 8));
        oacc[nb] = __builtin_amdgcn_mfma_f32_32x32x16_bf16(pa[ks], vf, oacc[nb], 0, 0, 0);
      }
    __builtin_amdgcn_s_setprio(0);

    __syncthreads();
    cur ^= 1;
  }

  // ---- epilogue ----
  float invl = 1.0f / lrun;
  bf16* Ob = O + ((size_t)(b * SEQ + q0 + w * 32)) * EMBED + h * DEPTH + l31;
#pragma unroll
  for (int r = 0; r < 16; r++) {
    int cr = (r & 3) + 8 * (r >> 2) + 4 * hi;
    float iv = __shfl(invl, cr);
    Ob[(size_t)cr * EMBED + 0] = (bf16)(oacc[0][r] * iv);
    Ob[(size_t)cr * EMBED + 32] = (bf16)(oacc[1][r] * iv);
  }
}

// ---------------- launch ----------------
extern "C" void kernel_launch(void* const* d_in, const int* in_sizes, int n_in,
                              void* d_out, int out_size, void* d_ws, size_t ws_size,
                              hipStream_t stream) {
  (void)in_sizes; (void)n_in; (void)out_size; (void)ws_size;
  const float* q = (const float*)d_in[0];
  const float* k = (const float*)d_in[1];
  const float* v = (const float*)d_in[2];
  const float* mask = (const float*)d_in[3];
  const float* Wq = (const float*)d_in[4];
  const float* bq = (const float*)d_in[5];
  const float* Wk = (const float*)d_in[6];
  const float* bk = (const float*)d_in[7];
  const float* Wv = (const float*)d_in[8];
  const float* bv = (const float*)d_in[9];
  const float* Wo = (const float*)d_in[10];
  const float* bo = (const float*)d_in[11];

  const size_t NX = (size_t)M_TOTAL * EMBED;
  const size_t NW = (size_t)EMBED * EMBED;
  bf16* Xq = (bf16*)d_ws;
  bf16* Xk = Xq + NX;
  bf16* Xv = Xk + NX;
  bf16* WTq = Xv + NX;
  bf16* WTk = WTq + NW;
  bf16* WTv = WTk + NW;
  bf16* WTo = WTv + NW;
  bf16* qh = WTo + NW;
  bf16* kh = qh + NX;
  bf16* vT = kh + NX;
  bf16* Ow = vT + NX;

  cvt3<<<dim3(NX / 2048, 3), 256, 0, stream>>>(q, k, v, Xq, Xk, Xv);
  transpose4<<<dim3(16, 16, 4), 256, 0, stream>>>(Wq, Wk, Wv, Wo, WTq, WTk, WTv, WTo);

  gemm_qkv<<<dim3(EMBED / 128, M_TOTAL / 128, 3), 256, 0, stream>>>(
      Xq, Xk, Xv, WTq, WTk, WTv, bq, bk, bv, qh, kh, vT);

  flash_attn<<<dim3(SEQ / 128, BATCH * NHEAD), 256, 0, stream>>>(qh, kh, vT, mask, Ow);

  gemm_o<<<dim3(EMBED / 128, M_TOTAL / 128), 256, 0, stream>>>(Ow, WTo, bo, (float*)d_out);
}

// Round 4
// 251.902 us; speedup vs baseline: 1.6595x; 1.0145x over previous
//
#include <hip/hip_runtime.h>
#include <stdint.h>

typedef __bf16 bf16;
typedef bf16 bf16x8 __attribute__((ext_vector_type(8)));
typedef float f32x4 __attribute__((ext_vector_type(4)));
typedef float f32x16 __attribute__((ext_vector_type(16)));

#define EMBED 512
#define NHEAD 8
#define DEPTH 64
#define BATCH 2
#define SEQ 4096
#define M_TOTAL (BATCH * SEQ)
#define KVH 2048            // keys per wave-half (split-KV)
#define NT (KVH / 64)       // 32 tiles per half

#define LOG2E 1.44269504f
#define QSCALE (0.125f * LOG2E)  // folded into q projection (log2 domain)
#define MASKC (-1.0e9f * LOG2E)
#define DEFER_THR 10.0f

// ---------------- helpers ----------------
__device__ __forceinline__ void gload16(const void* g, void* l) {
  __builtin_amdgcn_global_load_lds((const __attribute__((address_space(1))) unsigned*)g,
                                   (__attribute__((address_space(3))) unsigned*)l, 16, 0, 0);
}
__device__ __forceinline__ uint32_t cvtpk(float a, float b) {
  uint32_t r;
  asm volatile("v_cvt_pk_bf16_f32 %0, %1, %2" : "=v"(r) : "v"(a), "v"(b));
  return r;
}
__device__ __forceinline__ void plswap(uint32_t& a, uint32_t& b) {
  asm volatile("v_permlane32_swap_b32 %0, %1" : "+v"(a), "+v"(b));
}
__device__ __forceinline__ float vdup(float x) {
  float r;
  asm volatile("v_mov_b32 %0, %1" : "=v"(r) : "v"(x));
  return r;
}
__device__ __forceinline__ float cross_max(float x) {
  float a = x, b = vdup(x);
  asm volatile("v_permlane32_swap_b32 %0, %1" : "+v"(a), "+v"(b));
  return fmaxf(a, b);
}
__device__ __forceinline__ float cross_sum(float x) {
  float a = x, b = vdup(x);
  asm volatile("v_permlane32_swap_b32 %0, %1" : "+v"(a), "+v"(b));
  return a + b;
}
union U4 { uint32_t u[4]; bf16x8 v; };

// ---------------- fused fp32 -> bf16 convert ----------------
__global__ __launch_bounds__(256) void cvt3(const float* __restrict__ q, const float* __restrict__ k,
                                            const float* __restrict__ v, bf16* __restrict__ oq,
                                            bf16* __restrict__ ok, bf16* __restrict__ ov) {
  int z = blockIdx.y;
  const float* in = z == 0 ? q : (z == 1 ? k : v);
  bf16* out = z == 0 ? oq : (z == 1 ? ok : ov);
  size_t i = ((size_t)blockIdx.x * 256 + threadIdx.x) * 8;
  float4 f0 = *(const float4*)(in + i);
  float4 f1 = *(const float4*)(in + i + 4);
  bf16x8 o;
  o[0] = (bf16)f0.x; o[1] = (bf16)f0.y; o[2] = (bf16)f0.z; o[3] = (bf16)f0.w;
  o[4] = (bf16)f1.x; o[5] = (bf16)f1.y; o[6] = (bf16)f1.z; o[7] = (bf16)f1.w;
  *(bf16x8*)(out + i) = o;
}

// ---------------- W[k][n] -> WT[n][k] bf16 ----------------
__global__ __launch_bounds__(256) void transpose4(const float* __restrict__ W0, const float* __restrict__ W1,
                                                  const float* __restrict__ W2, const float* __restrict__ W3,
                                                  bf16* __restrict__ T0, bf16* __restrict__ T1,
                                                  bf16* __restrict__ T2, bf16* __restrict__ T3) {
  int z = blockIdx.z;
  const float* W = z == 0 ? W0 : (z == 1 ? W1 : (z == 2 ? W2 : W3));
  bf16* WT = z == 0 ? T0 : (z == 1 ? T1 : (z == 2 ? T2 : T3));
  __shared__ float t[32][33];
  int k0 = blockIdx.x * 32, n0 = blockIdx.y * 32;
  int x = threadIdx.x & 31, y = threadIdx.x >> 5;
#pragma unroll
  for (int yy = y; yy < 32; yy += 8)
    t[yy][x] = W[(size_t)(k0 + yy) * EMBED + n0 + x];
  __syncthreads();
#pragma unroll
  for (int yy = y; yy < 32; yy += 8)
    WT[(size_t)(n0 + yy) * EMBED + k0 + x] = (bf16)t[x][yy];
}

// ---------------- 128x128 GEMM body ----------------
__device__ __forceinline__ void gemm128_body(const bf16* __restrict__ A, const bf16* __restrict__ Bt,
                                             const float* __restrict__ bias, void* __restrict__ out,
                                             float scale, int mode) {
  __shared__ __align__(16) bf16 As[128 * 64];
  __shared__ __align__(16) bf16 Bs[128 * 64];
  int tid = threadIdx.x, lane = tid & 63, w = tid >> 6;
  int g = lane >> 4, r = lane & 15;
  int n0 = blockIdx.x * 128, m0 = blockIdx.y * 128;
  int wr = (w >> 1) * 64, wc = (w & 1) * 64;

  f32x4 acc[4][4];
#pragma unroll
  for (int m = 0; m < 4; m++)
#pragma unroll
    for (int n = 0; n < 4; n++)
#pragma unroll
      for (int i = 0; i < 4; i++) acc[m][n][i] = 0.f;

  size_t aoff[4], boff[4];
#pragma unroll
  for (int i = 0; i < 4; i++) {
    int u = w * 64 + lane + i * 256;
    int row = u >> 3, scs = (u & 7) ^ (row & 7);
    aoff[i] = (size_t)(m0 + row) * EMBED + scs * 8;
    boff[i] = (size_t)(n0 + row) * EMBED + scs * 8;
  }

  for (int k0 = 0; k0 < EMBED; k0 += 64) {
#pragma unroll
    for (int i = 0; i < 4; i++) {
      gload16(A + aoff[i] + k0, &As[(w + i * 4) * 512]);
      gload16(Bt + boff[i] + k0, &Bs[(w + i * 4) * 512]);
    }
    __syncthreads();
#pragma unroll
    for (int kk = 0; kk < 64; kk += 32) {
      bf16x8 af[4], bf_[4];
#pragma unroll
      for (int m = 0; m < 4; m++) {
        int row = wr + m * 16 + r;
        af[m] = *(const bf16x8*)&As[row * 64 + (((kk >> 3) + g) ^ (r & 7)) * 8];
      }
#pragma unroll
      for (int n = 0; n < 4; n++) {
        int col = wc + n * 16 + r;
        bf_[n] = *(const bf16x8*)&Bs[col * 64 + (((kk >> 3) + g) ^ (r & 7)) * 8];
      }
      __builtin_amdgcn_s_setprio(1);
#pragma unroll
      for (int m = 0; m < 4; m++)
#pragma unroll
        for (int n = 0; n < 4; n++)
          acc[m][n] = __builtin_amdgcn_mfma_f32_16x16x32_bf16(af[m], bf_[n], acc[m][n], 0, 0, 0);
      __builtin_amdgcn_s_setprio(0);
    }
    __syncthreads();
  }

#pragma unroll
  for (int n = 0; n < 4; n++) {
    int ncol = n0 + wc + n * 16 + r;
    float bv = bias[ncol];
#pragma unroll
    for (int m = 0; m < 4; m++)
#pragma unroll
      for (int v_ = 0; v_ < 4; v_++) {
        int mrow = m0 + wr + m * 16 + g * 4 + v_;
        float val = (acc[m][n][v_] + bv) * scale;
        if (mode == 2) {
          ((float*)out)[(size_t)mrow * EMBED + ncol] = val;
        } else {
          int b = mrow >> 12, s = mrow & (SEQ - 1);
          int h = ncol >> 6, d = ncol & 63;
          size_t idx = (mode == 0) ? ((((size_t)(b * NHEAD + h)) * SEQ + s) * DEPTH + d)
                                   : ((((size_t)(b * NHEAD + h)) * DEPTH + d) * SEQ + s);
          ((bf16*)out)[idx] = (bf16)val;
        }
      }
  }
}

__global__ __launch_bounds__(256, 2) void gemm_qkv(const bf16* __restrict__ Xq, const bf16* __restrict__ Xk,
                                                   const bf16* __restrict__ Xv, const bf16* __restrict__ Tq,
                                                   const bf16* __restrict__ Tk, const bf16* __restrict__ Tv,
                                                   const float* __restrict__ bq, const float* __restrict__ bk,
                                                   const float* __restrict__ bv, bf16* __restrict__ qh,
                                                   bf16* __restrict__ kh, bf16* __restrict__ vT) {
  int z = blockIdx.z;
  const bf16* A = z == 0 ? Xq : (z == 1 ? Xk : Xv);
  const bf16* Bt = z == 0 ? Tq : (z == 1 ? Tk : Tv);
  const float* bias = z == 0 ? bq : (z == 1 ? bk : bv);
  void* out = z == 0 ? (void*)qh : (z == 1 ? (void*)kh : (void*)vT);
  float scale = z == 0 ? QSCALE : 1.0f;
  int mode = z == 2 ? 1 : 0;
  gemm128_body(A, Bt, bias, out, scale, mode);
}

__global__ __launch_bounds__(256, 2) void gemm_o(const bf16* __restrict__ A, const bf16* __restrict__ Bt,
                                                 const float* __restrict__ bias, float* __restrict__ out) {
  gemm128_body(A, Bt, bias, out, 1.0f, 2);
}

// ---------------- flash attention: 64 q/wave, split-KV, 8-wave blocks ----------------
// grid (SEQ/256, B*H) = 256 blocks, 512 thr. Wave w: qsub = w&3 (64 q-rows),
// half = w>>2 (keys [half*2048, half*2048+2048)). Per tile: 16 b128, 32 MFMA.
// Epilogue: merge halves via LDS (K/V buffers reused as O-exchange).
__global__ __launch_bounds__(512, 2) void flash_attn(const bf16* __restrict__ qh,
                                                     const bf16* __restrict__ kh,
                                                     const bf16* __restrict__ vT,
                                                     const float* __restrict__ mask,
                                                     bf16* __restrict__ O) {
  __shared__ __align__(16) unsigned char smem[65536];  // K/V dbuf, then O-exchange
  __shared__ float Sm[4][64];
  __shared__ float Sl[4][64];
  bf16* KV = (bf16*)smem;
  // elem offsets: K(buf,hh) = buf*16384 + hh*4096 ; V(buf,hh) = buf*16384 + 8192 + hh*4096

  int tid = threadIdx.x;
  int lane = tid & 63, w = tid >> 6;
  int l31 = lane & 31, hi = lane >> 5, l7 = lane & 7;
  int qs = w & 3, half = w >> 2;
  int bh = blockIdx.y, b = bh >> 3, h = bh & 7;
  int q0 = blockIdx.x * 256;
  const bf16* Qb = qh + (size_t)bh * SEQ * DEPTH;
  const bf16* Kb = kh + (size_t)bh * SEQ * DEPTH;
  const bf16* Vb = vT + (size_t)bh * DEPTH * SEQ;
  const float* maskb = mask + (size_t)b * SEQ + half * KVH;

  // staging: thread stages unit tid (16B) of each of 4 tiles (K h0,K h1,V h0,V h1).
  // source col pre-swizzled (rule 21): scs = (tid&7) ^ (row&7)
  int srow = tid >> 3;
  int scs = (tid & 7) ^ (srow & 7);
  const bf16* kg0 = Kb + (size_t)srow * DEPTH + scs * 8;
  const bf16* vg0 = Vb + (size_t)srow * SEQ + scs * 8;
  int wofs = w * 512;  // wave-uniform dest base (elems); HW adds lane*16B

#define STAGE(buf, kv)                                                              \
  do {                                                                              \
    gload16(kg0 + (size_t)(kv)*DEPTH, KV + (buf)*16384 + wofs);                     \
    gload16(kg0 + (size_t)((kv) + KVH) * DEPTH, KV + (buf)*16384 + 4096 + wofs);    \
    gload16(vg0 + (kv), KV + (buf)*16384 + 8192 + wofs);                            \
    gload16(vg0 + ((kv) + KVH), KV + (buf)*16384 + 12288 + wofs);                   \
  } while (0)

  STAGE(0, 0);

  // Q fragments (B-operand), 64 q-rows = 2 x 32-groups, resident whole kernel
  bf16x8 qf[2][4];
#pragma unroll
  for (int q2 = 0; q2 < 2; q2++) {
    const bf16* qp = Qb + (size_t)(q0 + qs * 64 + q2 * 32 + l31) * DEPTH + hi * 8;
#pragma unroll
    for (int s = 0; s < 4; s++) qf[q2][s] = *(const bf16x8*)(qp + s * 16);
  }

  f32x16 oacc[2][2];
#pragma unroll
  for (int q2 = 0; q2 < 2; q2++)
#pragma unroll
    for (int nb = 0; nb < 2; nb++)
#pragma unroll
      for (int i = 0; i < 16; i++) oacc[q2][nb][i] = 0.f;
  float mrun[2] = {-__builtin_inff(), -__builtin_inff()};
  float lrun[2] = {0.f, 0.f};

  __syncthreads();

  int cur = 0;
  for (int t = 0; t < NT; ++t) {
    int kv = t * 64;
    if (t + 1 < NT) STAGE(cur ^ 1, kv + 64);

    const bf16* Kcur = KV + cur * 16384 + half * 4096;
    const bf16* Vcur = KV + cur * 16384 + 8192 + half * 4096;

    // hoisted mask loads (same keys for both q2)
    f32x4 mf[2][4];
#pragma unroll
    for (int m2 = 0; m2 < 2; m2++)
#pragma unroll
      for (int g = 0; g < 4; g++)
        mf[m2][g] = *(const f32x4*)(maskb + kv + m2 * 32 + g * 8 + 4 * hi);

    // K frags, shared across both q2
    bf16x8 kf[2][4];
#pragma unroll
    for (int m2 = 0; m2 < 2; m2++)
#pragma unroll
      for (int s = 0; s < 4; s++)
        kf[m2][s] = *(const bf16x8*)(Kcur + (m2 * 32 + l31) * 64 + (((s * 2 + hi) ^ l7) * 8));

    bf16x8 pa[2][4];
#pragma unroll
    for (int q2 = 0; q2 < 2; q2++) {
      // ---- S^T = K Q^T ----
      f32x16 sacc[2];
#pragma unroll
      for (int m2 = 0; m2 < 2; m2++)
#pragma unroll
        for (int i = 0; i < 16; i++) sacc[m2][i] = 0.f;
      __builtin_amdgcn_s_setprio(1);
#pragma unroll
      for (int m2 = 0; m2 < 2; m2++)
#pragma unroll
        for (int s = 0; s < 4; s++)
          sacc[m2] = __builtin_amdgcn_mfma_f32_32x32x16_bf16(kf[m2][s], qf[q2][s], sacc[m2], 0, 0, 0);
      __builtin_amdgcn_s_setprio(0);

      // ---- mask fma ----
#pragma unroll
      for (int m2 = 0; m2 < 2; m2++)
#pragma unroll
        for (int g = 0; g < 4; g++)
#pragma unroll
          for (int i = 0; i < 4; i++)
            sacc[m2][4 * g + i] = fmaf(mf[m2][g][i], MASKC, sacc[m2][4 * g + i]);

      // ---- row max (tree) + cross-half ----
      float tmx[16];
#pragma unroll
      for (int i = 0; i < 16; i++) tmx[i] = fmaxf(sacc[0][i], sacc[1][i]);
#pragma unroll
      for (int i = 0; i < 8; i++) tmx[i] = fmaxf(tmx[i], tmx[i + 8]);
#pragma unroll
      for (int i = 0; i < 4; i++) tmx[i] = fmaxf(tmx[i], tmx[i + 4]);
      float pmax = fmaxf(fmaxf(tmx[0], tmx[1]), fmaxf(tmx[2], tmx[3]));
      pmax = cross_max(pmax);

      // ---- defer-max (T13) ----
      if (__any(pmax > mrun[q2] + DEFER_THR)) {
        float mnew = fmaxf(mrun[q2], pmax);
        float alpha = exp2f(mrun[q2] - mnew);
        lrun[q2] *= alpha;
        mrun[q2] = mnew;
#pragma unroll
        for (int r = 0; r < 16; r++) {
          float af = __shfl(alpha, (r & 3) + 8 * (r >> 2) + 4 * hi);
          oacc[q2][0][r] *= af;
          oacc[q2][1][r] *= af;
        }
      }

      // ---- P = exp2(S - m), row sum ----
      float p[32];
      float rsv[4] = {0.f, 0.f, 0.f, 0.f};
#pragma unroll
      for (int m2 = 0; m2 < 2; m2++)
#pragma unroll
        for (int i = 0; i < 16; i++) {
          float pv = __builtin_amdgcn_exp2f(sacc[m2][i] - mrun[q2]);
          p[m2 * 16 + i] = pv;
          rsv[i & 3] += pv;
        }
      float rsum = (rsv[0] + rsv[1]) + (rsv[2] + rsv[3]);
      lrun[q2] += cross_sum(rsum);

      // ---- P -> A-frags (T12) ----
#pragma unroll
      for (int m2 = 0; m2 < 2; m2++) {
        uint32_t c0 = cvtpk(p[m2 * 16 + 0], p[m2 * 16 + 1]);
        uint32_t c1 = cvtpk(p[m2 * 16 + 2], p[m2 * 16 + 3]);
        uint32_t d0 = cvtpk(p[m2 * 16 + 4], p[m2 * 16 + 5]);
        uint32_t d1 = cvtpk(p[m2 * 16 + 6], p[m2 * 16 + 7]);
        plswap(c0, d0);
        plswap(c1, d1);
        U4 e; e.u[0] = c0; e.u[1] = c1; e.u[2] = d0; e.u[3] = d1;
        pa[q2][m2 * 2 + 0] = e.v;
        uint32_t c2 = cvtpk(p[m2 * 16 + 8], p[m2 * 16 + 9]);
        uint32_t c3 = cvtpk(p[m2 * 16 + 10], p[m2 * 16 + 11]);
        uint32_t d2 = cvtpk(p[m2 * 16 + 12], p[m2 * 16 + 13]);
        uint32_t d3 = cvtpk(p[m2 * 16 + 14], p[m2 * 16 + 15]);
        plswap(c2, d2);
        plswap(c3, d3);
        U4 o; o.u[0] = c2; o.u[1] = c3; o.u[2] = d2; o.u[3] = d3;
        pa[q2][m2 * 2 + 1] = o.v;
      }
    }

    // ---- O += P V (V frags shared across q2) ----
    __builtin_amdgcn_s_setprio(1);
#pragma unroll
    for (int nb = 0; nb < 2; nb++)
#pragma unroll
      for (int ks = 0; ks < 4; ks++) {
        bf16x8 vf = *(const bf16x8*)(Vcur + (nb * 32 + l31) * 64 + (((ks * 2 + hi) ^ l7) * 8));
        oacc[0][nb] = __builtin_amdgcn_mfma_f32_32x32x16_bf16(pa[0][ks], vf, oacc[0][nb], 0, 0, 0);
        oacc[1][nb] = __builtin_amdgcn_mfma_f32_32x32x16_bf16(pa[1][ks], vf, oacc[1][nb], 0, 0, 0);
      }
    __builtin_amdgcn_s_setprio(0);

    __syncthreads();
    cur ^= 1;
  }

  // ---- epilogue: merge the two KV-halves via LDS, then write [B][S][E] bf16 ----
  float* Oex = (float*)smem;  // [qsub][64 q][64 d] f32 = 16KB x 4
  if (half == 1) {
    if (hi == 0) {
#pragma unroll
      for (int q2 = 0; q2 < 2; q2++) {
        Sm[qs][q2 * 32 + l31] = mrun[q2];
        Sl[qs][q2 * 32 + l31] = lrun[q2];
      }
    }
    float* Op = Oex + qs * 4096;
#pragma unroll
    for (int q2 = 0; q2 < 2; q2++)
#pragma unroll
      for (int nb = 0; nb < 2; nb++)
#pragma unroll
        for (int r = 0; r < 16; r++) {
          int cr = (r & 3) + 8 * (r >> 2) + 4 * hi;
          Op[(q2 * 32 + cr) * 64 + nb * 32 + l31] = oacc[q2][nb][r];
        }
  }
  __syncthreads();
  if (half == 0) {
    float s0[2], s1[2];
#pragma unroll
    for (int q2 = 0; q2 < 2; q2++) {
      float m1 = Sm[qs][q2 * 32 + l31];
      float l1 = Sl[qs][q2 * 32 + l31];
      float mm = fmaxf(mrun[q2], m1);
      float e0 = exp2f(mrun[q2] - mm);
      float e1 = exp2f(m1 - mm);
      float inv = 1.0f / (lrun[q2] * e0 + l1 * e1);
      s0[q2] = e0 * inv;
      s1[q2] = e1 * inv;
    }
    float* Op = Oex + qs * 4096;
    bf16* Ob = O + ((size_t)(b * SEQ + q0 + qs * 64)) * EMBED + h * DEPTH + l31;
#pragma unroll
    for (int q2 = 0; q2 < 2; q2++)
#pragma unroll
      for (int nb = 0; nb < 2; nb++)
#pragma unroll
        for (int r = 0; r < 16; r++) {
          int cr = (r & 3) + 8 * (r >> 2) + 4 * hi;
          float a0 = __shfl(s0[q2], cr);
          float a1 = __shfl(s1[q2], cr);
          float o1 = Op[(q2 * 32 + cr) * 64 + nb * 32 + l31];
          Ob[(size_t)(q2 * 32 + cr) * EMBED + nb * 32] = (bf16)(oacc[q2][nb][r] * a0 + o1 * a1);
        }
  }
#undef STAGE
}

// ---------------- launch ----------------
extern "C" void kernel_launch(void* const* d_in, const int* in_sizes, int n_in,
                              void* d_out, int out_size, void* d_ws, size_t ws_size,
                              hipStream_t stream) {
  (void)in_sizes; (void)n_in; (void)out_size; (void)ws_size;
  const float* q = (const float*)d_in[0];
  const float* k = (const float*)d_in[1];
  const float* v = (const float*)d_in[2];
  const float* mask = (const float*)d_in[3];
  const float* Wq = (const float*)d_in[4];
  const float* bq = (const float*)d_in[5];
  const float* Wk = (const float*)d_in[6];
  const float* bk = (const float*)d_in[7];
  const float* Wv = (const float*)d_in[8];
  const float* bv = (const float*)d_in[9];
  const float* Wo = (const float*)d_in[10];
  const float* bo = (const float*)d_in[11];

  const size_t NX = (size_t)M_TOTAL * EMBED;
  const size_t NW = (size_t)EMBED * EMBED;
  bf16* Xq = (bf16*)d_ws;
  bf16* Xk = Xq + NX;
  bf16* Xv = Xk + NX;
  bf16* WTq = Xv + NX;
  bf16* WTk = WTq + NW;
  bf16* WTv = WTk + NW;
  bf16* WTo = WTv + NW;
  bf16* qh = WTo + NW;
  bf16* kh = qh + NX;
  bf16* vT = kh + NX;
  bf16* Ow = vT + NX;

  cvt3<<<dim3(NX / 2048, 3), 256, 0, stream>>>(q, k, v, Xq, Xk, Xv);
  transpose4<<<dim3(16, 16, 4), 256, 0, stream>>>(Wq, Wk, Wv, Wo, WTq, WTk, WTv, WTo);

  gemm_qkv<<<dim3(EMBED / 128, M_TOTAL / 128, 3), 256, 0, stream>>>(
      Xq, Xk, Xv, WTq, WTk, WTv, bq, bk, bv, qh, kh, vT);

  flash_attn<<<dim3(SEQ / 256, BATCH * NHEAD), 512, 0, stream>>>(qh, kh, vT, mask, Ow);

  gemm_o<<<dim3(EMBED / 128, M_TOTAL / 128), 256, 0, stream>>>(Ow, WTo, bo, (float*)d_out);
}